// Round 4
// baseline (225.323 us; speedup 1.0000x reference)
//
#include <hip/hip_runtime.h>
#include <stdint.h>

#define NNODES 1024
#define NGRAPH 128
#define TOPK   16384
#define EQCAP  4096

// Order-preserving monotone map fp32 -> u32 (larger float => larger key).
__device__ __forceinline__ uint32_t fkey(float x) {
    uint32_t u = __float_as_uint(x);
    return (u & 0x80000000u) ? ~u : (u | 0x80000000u);
}

// ---------------------------------------------------------------------------
// Fused selection kernel: per graph (one 1024-thread block):
//   1. bitonic-sort t by key (values+indices, all in LDS)
//   2. 8-ary search of the 32-bit key space for the K-th largest product key T
//      (7 interleaved per-row binary searches per iteration -> 7 concurrent
//      LDS dependency chains; 13 iterations cover the full 2^32 range)
//   3. exact count at T -> R = K - count_gt(T)
//   4. collect flat indices of elements with key == T (ties) into LDS, then
//      one coalesced dump to global.
// Product s_i*t_j is monotone in t_j for fixed s_i (IEEE multiply), so
// count(key > T) per row is a binary search over sorted t.
//
// Fixed-trip-count search correctness (R2/R3 bug history):
//  - body at lo==hi==q<1024 is idempotent (boundary element votes "go left")
//  - body at lo==hi==1024 read tvs[1024] OOB (garbage from wsum) -> count
//    corrupted. Fix: clamp mid to NNODES-1; at q==1024 the clamped element
//    (position q-1) always votes "go right" -> lo=mid+1=1024, a no-op.
// ---------------------------------------------------------------------------
__global__ __launch_bounds__(NNODES)
void select_kernel(const float* __restrict__ s, const float* __restrict__ t,
                   uint32_t* __restrict__ Tout, uint32_t* __restrict__ Rout,
                   uint32_t* __restrict__ eqCntG, uint32_t* __restrict__ eqIdxG) {
    const int g = blockIdx.x, i = threadIdx.x;
    __shared__ float    torig[NNODES];
    __shared__ uint32_t skey[NNODES];
    __shared__ uint16_t sidx[NNODES];
    __shared__ float    tvs[NNODES];     // t values in key-ascending order
    __shared__ uint32_t wsum[16][7];
    __shared__ uint32_t sTot[7];
    __shared__ uint32_t sLo, sHi, sEqCnt;
    __shared__ uint32_t sEqList[EQCAP];

    const float tv_i = t[g * NNODES + i];
    torig[i] = tv_i;
    skey[i]  = fkey(tv_i);
    sidx[i]  = (uint16_t)i;
    if (i == 0) { sLo = 0u; sHi = 0xFFFFFFFFu; sEqCnt = 0u; }

    // ---- bitonic sort (keys + payload indices) ----
    for (int k = 2; k <= NNODES; k <<= 1) {
        for (int j = k >> 1; j > 0; j >>= 1) {
            __syncthreads();
            int partner = i ^ j;
            if (partner > i) {
                bool asc = ((i & k) == 0);
                uint32_t a = skey[i], b = skey[partner];
                if ((a > b) == asc) {
                    skey[i] = b; skey[partner] = a;
                    uint16_t ia = sidx[i]; sidx[i] = sidx[partner]; sidx[partner] = ia;
                }
            }
        }
    }
    __syncthreads();
    tvs[i] = torig[sidx[i]];

    const float sv = s[g * NNODES + i];
    const bool sneg = (__float_as_uint(sv) >> 31) != 0;
    const uint32_t kdiag = fkey(sv * tv_i);   // diagonal element (excluded)
    __syncthreads();

    // count(key > cand[p]) over the whole matrix (diag excluded), 7 candidates
    // at once. Per row: binary search over sorted t (suffix for s>=+0, prefix
    // for s<0). The 7 searches are independent -> their LDS chains overlap.
    auto cnt_multi = [&](const uint32_t cand[7], uint32_t cnt[7]) {
        int lo7[7], hi7[7];
        #pragma unroll
        for (int p = 0; p < 7; ++p) { lo7[p] = 0; hi7[p] = NNODES; }
        for (int st = 0; st < 11; ++st) {      // 11 steps: ceil(log2(1025))
            #pragma unroll
            for (int p = 0; p < 7; ++p) {
                int mid = (lo7[p] + hi7[p]) >> 1;
                if (mid > NNODES - 1) mid = NNODES - 1;   // OOB guard (see header)
                bool pred = fkey(sv * tvs[mid]) > cand[p];
                bool goLeft = sneg ? !pred : pred;
                if (goLeft) hi7[p] = mid; else lo7[p] = mid + 1;
            }
        }
        #pragma unroll
        for (int p = 0; p < 7; ++p) {
            uint32_t c = sneg ? (uint32_t)lo7[p] : (uint32_t)(NNODES - lo7[p]);
            if (kdiag > cand[p]) c--;
            uint32_t r = c;
            for (int off = 32; off; off >>= 1) r += __shfl_down(r, off);
            if ((i & 63) == 0) wsum[i >> 6][p] = r;
        }
        __syncthreads();
        if (i < 7) {
            uint32_t tot = 0;
            for (int w = 0; w < 16; ++w) tot += wsum[w][i];
            sTot[i] = tot;
        }
        __syncthreads();
        #pragma unroll
        for (int p = 0; p < 7; ++p) cnt[p] = sTot[p];
    };

    // ---- 8-ary search: minimal T with cnt_gt(T) < K ----
    for (int it = 0; it < 13; ++it) {
        uint32_t lo = sLo, hi = sHi;
        uint64_t range = (uint64_t)(hi - lo);
        uint32_t cand[7], cnt[7];
        #pragma unroll
        for (int p = 0; p < 7; ++p) cand[p] = lo + (uint32_t)((range * (p + 1)) >> 3);
        cnt_multi(cand, cnt);
        __syncthreads();
        if (i == 0 && lo < hi) {
            int pstar = -1;
            #pragma unroll
            for (int p = 0; p < 7; ++p) if (pstar < 0 && cnt[p] < TOPK) pstar = p;
            if (pstar < 0)      { sLo = cand[6] + 1; }
            else                { sHi = cand[pstar]; if (pstar > 0) sLo = cand[pstar - 1] + 1; }
        }
        __syncthreads();
    }
    const uint32_t T = sLo;

    // ---- exact count at T -> R ----
    {
        uint32_t cand[7], cnt[7];
        #pragma unroll
        for (int p = 0; p < 7; ++p) cand[p] = T;
        cnt_multi(cand, cnt);
        if (i == 0) { Tout[g] = T; Rout[g] = TOPK - cnt[0]; }
    }
    __syncthreads();

    // ---- collect ties (key == T), diagonal excluded ----
    auto bound = [&](bool ge) -> int {
        int lo = 0, hi = NNODES;
        while (lo < hi) {
            int mid = (lo + hi) >> 1;
            uint32_t k = fkey(sv * tvs[mid]);
            bool pred = ge ? (k >= T) : (k > T);
            bool goLeft = sneg ? !pred : pred;
            if (goLeft) hi = mid; else lo = mid + 1;
        }
        return lo;
    };
    int e0, e1;
    if (!sneg) { e0 = bound(true);  e1 = bound(false); }   // equals = [ge_start, gt_start)
    else       { e0 = bound(false); e1 = bound(true);  }   // equals = [gt_end, ge_end)
    for (int p = e0; p < e1; ++p) {
        uint32_t j = sidx[p];
        if ((int)j == i) continue;
        uint32_t slot = atomicAdd(&sEqCnt, 1u);
        if (slot < EQCAP) sEqList[slot] = (uint32_t)(i * NNODES) + j;
    }
    __syncthreads();
    uint32_t E = sEqCnt; if (E > EQCAP) E = EQCAP;
    if (i == 0) eqCntG[g] = E;
    for (uint32_t p = i; p < E; p += NNODES) eqIdxG[g * EQCAP + p] = sEqList[p];
}

// ---------------------------------------------------------------------------
// Output write: out = (key > T) && (i != j). One block per output row;
// float4 stores (1 KiB per wave instruction). ~512 MiB -> HBM-write-bound.
// ---------------------------------------------------------------------------
__global__ __launch_bounds__(256)
void write_kernel(const float* __restrict__ s, const float* __restrict__ t,
                  const uint32_t* __restrict__ Tin, float* __restrict__ out) {
    const int b = blockIdx.x;           // g*1024 + i
    const int g = b >> 10, i = b & 1023;
    const uint32_t T = Tin[g];
    const float sv = s[(size_t)g * NNODES + i];
    const float4 tv = ((const float4*)(t + (size_t)g * NNODES))[threadIdx.x];
    const int j0 = threadIdx.x * 4;
    float4 r;
    r.x = (fkey(sv * tv.x) > T && (j0 + 0) != i) ? 1.0f : 0.0f;
    r.y = (fkey(sv * tv.y) > T && (j0 + 1) != i) ? 1.0f : 0.0f;
    r.z = (fkey(sv * tv.z) > T && (j0 + 2) != i) ? 1.0f : 0.0f;
    r.w = (fkey(sv * tv.w) > T && (j0 + 3) != i) ? 1.0f : 0.0f;
    ((float4*)(out + (size_t)g * NNODES * NNODES + (size_t)i * NNODES))[threadIdx.x] = r;
}

// ---------------------------------------------------------------------------
// Among ties, set the R smallest flat indices to 1 (matches jax.lax.top_k
// tie-breaking: lower flat index wins).
// ---------------------------------------------------------------------------
__global__ __launch_bounds__(256)
void scatter_kernel(const uint32_t* __restrict__ eqCnt, const uint32_t* __restrict__ eqIdx,
                    const uint32_t* __restrict__ Rin, float* __restrict__ out) {
    const int g = blockIdx.x;
    uint32_t E = eqCnt[g];
    const uint32_t R = Rin[g];
    __shared__ uint32_t se[EQCAP];
    for (uint32_t p = threadIdx.x; p < E; p += blockDim.x) se[p] = eqIdx[g * EQCAP + p];
    __syncthreads();
    for (uint32_t p = threadIdx.x; p < E; p += blockDim.x) {
        uint32_t v = se[p], rank = 0;
        for (uint32_t q = 0; q < E; ++q) rank += (se[q] < v) ? 1u : 0u;
        if (rank < R) out[(size_t)g * NNODES * NNODES + v] = 1.0f;
    }
}

extern "C" void kernel_launch(void* const* d_in, const int* in_sizes, int n_in,
                              void* d_out, int out_size, void* d_ws, size_t ws_size,
                              hipStream_t stream) {
    // inputs: x (unused), emb_s [G,N,1], emb_t [G,1,N] -- all float32
    const float* s = (const float*)d_in[1];
    const float* t = (const float*)d_in[2];
    float* out = (float*)d_out;

    char* ws = (char*)d_ws;
    uint32_t* Tbuf  = (uint32_t*)ws; ws += (size_t)NGRAPH * 4;
    uint32_t* Rbuf  = (uint32_t*)ws; ws += (size_t)NGRAPH * 4;
    uint32_t* eqCnt = (uint32_t*)ws; ws += (size_t)NGRAPH * 4;
    uint32_t* eqIdx = (uint32_t*)ws; ws += (size_t)NGRAPH * EQCAP * 4;

    select_kernel<<<NGRAPH, NNODES, 0, stream>>>(s, t, Tbuf, Rbuf, eqCnt, eqIdx);
    write_kernel<<<NGRAPH * NNODES, 256, 0, stream>>>(s, t, Tbuf, out);
    scatter_kernel<<<NGRAPH, 256, 0, stream>>>(eqCnt, eqIdx, Rbuf, out);
}

// Round 5
// 141.776 us; speedup vs baseline: 1.5893x; 1.5893x over previous
//
#include <hip/hip_runtime.h>
#include <stdint.h>

#define NNODES 1024
#define NGRAPH 128
#define TOPK   16384
#define EQCAP  4096

// Order-preserving monotone map fp32 -> u32 (larger float => larger key).
__device__ __forceinline__ uint32_t fkey(float x) {
    uint32_t u = __float_as_uint(x);
    return (u & 0x80000000u) ? ~u : (u | 0x80000000u);
}

// ---------------------------------------------------------------------------
// Fused selection kernel, one 1024-thread block per graph.
//   1. bitonic-sort t by key (values+indices in LDS)
//   2. 33-iter binary search of the 32-bit key space for the K-th largest
//      product key T. Per iteration each row does ONE binary search over
//      sorted t, restricted to a per-row interval [rlo,rhi] that provably
//      contains the boundary for every candidate in the current key interval
//      [sLo,sHi] (boundary is monotone in the candidate). Intervals shrink
//      geometrically -> total LDS reads ~70/lane instead of 33*11.
//      (R4 lesson: the block is LDS-THROUGHPUT-bound across 16 waves, so
//      read volume, not chain latency, is what matters.)
//   3. exact count at T -> R = K - count_gt(T)
//   4. collect ties (key == T, diag excluded) into LDS, dump to global.
// Product s_i*t_j is monotone in t_j for fixed s_i (IEEE multiply), so the
// per-row count boundary is binary-searchable; sign of s_i picks direction.
// ---------------------------------------------------------------------------
__global__ __launch_bounds__(NNODES)
void select_kernel(const float* __restrict__ s, const float* __restrict__ t,
                   uint32_t* __restrict__ Tout, uint32_t* __restrict__ Rout,
                   uint32_t* __restrict__ eqCntG, uint32_t* __restrict__ eqIdxG) {
    const int g = blockIdx.x, i = threadIdx.x;
    __shared__ float    torig[NNODES];
    __shared__ uint32_t skey[NNODES];
    __shared__ uint16_t sidx[NNODES];
    __shared__ float    tvs[NNODES];     // t values in key-ascending order
    __shared__ uint32_t wsum[16];
    __shared__ uint32_t sLo, sHi, sDir, sEqCnt;
    __shared__ uint32_t sEqList[EQCAP];

    const float tv_i = t[g * NNODES + i];
    torig[i] = tv_i;
    skey[i]  = fkey(tv_i);
    sidx[i]  = (uint16_t)i;
    if (i == 0) { sLo = 0u; sHi = 0xFFFFFFFFu; sEqCnt = 0u; }

    // ---- bitonic sort (keys + payload indices) ----
    for (int k = 2; k <= NNODES; k <<= 1) {
        for (int j = k >> 1; j > 0; j >>= 1) {
            __syncthreads();
            int partner = i ^ j;
            if (partner > i) {
                bool asc = ((i & k) == 0);
                uint32_t a = skey[i], b = skey[partner];
                if ((a > b) == asc) {
                    skey[i] = b; skey[partner] = a;
                    uint16_t ia = sidx[i]; sidx[i] = sidx[partner]; sidx[partner] = ia;
                }
            }
        }
    }
    __syncthreads();
    tvs[i] = torig[sidx[i]];

    const float sv = s[g * NNODES + i];
    const bool sneg = (__float_as_uint(sv) >> 31) != 0;
    const uint32_t kdiag = fkey(sv * tv_i);   // diagonal element (excluded)
    __syncthreads();

    // boundary search within [lo,hi); result b: for s>=+0 rows, predicate
    // (key>cand) true on suffix starting at b; for s<0 rows, true on prefix
    // ending at b. b is monotone in cand (non-decreasing for pos rows,
    // non-increasing for neg rows).
    auto srchRange = [&](uint32_t cand, int lo, int hi) -> int {
        while (lo < hi) {
            int mid = (lo + hi) >> 1;
            bool pred = fkey(sv * tvs[mid]) > cand;
            bool goLeft = sneg ? !pred : pred;
            if (goLeft) hi = mid; else lo = mid + 1;
        }
        return lo;
    };

    int rlo = 0, rhi = NNODES;   // per-row interval containing b(c) for all c in [sLo,sHi]

    // ---- binary search in key space: minimal T with cnt_gt(T) < K ----
    for (int it = 0; it < 33; ++it) {
        const uint32_t lo = sLo, hi = sHi;       // uniform (read after barrier)
        const uint32_t mid = lo + ((hi - lo) >> 1);
        const int b = srchRange(mid, rlo, rhi);
        uint32_t c = sneg ? (uint32_t)b : (uint32_t)(NNODES - b);
        if (kdiag > mid) c--;                    // exclude diagonal if it qualified
        uint32_t r = c;
        for (int off = 32; off; off >>= 1) r += __shfl_down(r, off);
        if ((i & 63) == 0) wsum[i >> 6] = r;
        __syncthreads();
        if (i == 0 && lo < hi) {
            uint32_t tot = 0;
            for (int w = 0; w < 16; ++w) tot += wsum[w];
            if (tot < TOPK) { sHi = mid; sDir = 0u; }   // go left
            else            { sLo = mid + 1; sDir = 1u; } // go right
        }
        __syncthreads();
        if (lo < hi) {
            // shrink per-row interval (monotonicity of b in cand):
            //  left  (new range <= mid):  pos rows b<=b(mid) -> rhi=b ; neg rows rlo=b
            //  right (new range >= mid+1): pos rows b>=b(mid) -> rlo=b ; neg rows rhi=b
            if (sDir == 0u) { if (!sneg) rhi = b; else rlo = b; }
            else            { if (!sneg) rlo = b; else rhi = b; }
        }
    }
    const uint32_t T = sLo;

    // ---- exact count at T -> R (T == sLo == sHi, interval still valid) ----
    {
        const int b = srchRange(T, rlo, rhi);
        uint32_t c = sneg ? (uint32_t)b : (uint32_t)(NNODES - b);
        if (kdiag > T) c--;
        uint32_t r = c;
        for (int off = 32; off; off >>= 1) r += __shfl_down(r, off);
        if ((i & 63) == 0) wsum[i >> 6] = r;
        __syncthreads();
        if (i == 0) {
            uint32_t tot = 0;
            for (int w = 0; w < 16; ++w) tot += wsum[w];
            Tout[g] = T; Rout[g] = TOPK - tot;
        }
    }
    __syncthreads();

    // ---- collect ties (key == T), diagonal excluded (full-range searches;
    //      the tracked interval does not cover the ">=T" == ">T-1" bound) ----
    auto bound = [&](bool ge) -> int {
        int lo = 0, hi = NNODES;
        while (lo < hi) {
            int mid = (lo + hi) >> 1;
            uint32_t k = fkey(sv * tvs[mid]);
            bool pred = ge ? (k >= T) : (k > T);
            bool goLeft = sneg ? !pred : pred;
            if (goLeft) hi = mid; else lo = mid + 1;
        }
        return lo;
    };
    int e0, e1;
    if (!sneg) { e0 = bound(true);  e1 = bound(false); }   // equals = [ge_start, gt_start)
    else       { e0 = bound(false); e1 = bound(true);  }   // equals = [gt_end, ge_end)
    for (int p = e0; p < e1; ++p) {
        uint32_t j = sidx[p];
        if ((int)j == i) continue;
        uint32_t slot = atomicAdd(&sEqCnt, 1u);
        if (slot < EQCAP) sEqList[slot] = (uint32_t)(i * NNODES) + j;
    }
    __syncthreads();
    uint32_t E = sEqCnt; if (E > EQCAP) E = EQCAP;
    if (i == 0) eqCntG[g] = E;
    for (uint32_t p = i; p < E; p += NNODES) eqIdxG[g * EQCAP + p] = sEqList[p];
}

// ---------------------------------------------------------------------------
// Output write: out = (key > T) && (i != j). One block per output row;
// float4 stores (1 KiB per wave instruction). ~512 MiB -> HBM-write-bound.
// ---------------------------------------------------------------------------
__global__ __launch_bounds__(256)
void write_kernel(const float* __restrict__ s, const float* __restrict__ t,
                  const uint32_t* __restrict__ Tin, float* __restrict__ out) {
    const int b = blockIdx.x;           // g*1024 + i
    const int g = b >> 10, i = b & 1023;
    const uint32_t T = Tin[g];
    const float sv = s[(size_t)g * NNODES + i];
    const float4 tv = ((const float4*)(t + (size_t)g * NNODES))[threadIdx.x];
    const int j0 = threadIdx.x * 4;
    float4 r;
    r.x = (fkey(sv * tv.x) > T && (j0 + 0) != i) ? 1.0f : 0.0f;
    r.y = (fkey(sv * tv.y) > T && (j0 + 1) != i) ? 1.0f : 0.0f;
    r.z = (fkey(sv * tv.z) > T && (j0 + 2) != i) ? 1.0f : 0.0f;
    r.w = (fkey(sv * tv.w) > T && (j0 + 3) != i) ? 1.0f : 0.0f;
    ((float4*)(out + (size_t)g * NNODES * NNODES + (size_t)i * NNODES))[threadIdx.x] = r;
}

// ---------------------------------------------------------------------------
// Among ties, set the R smallest flat indices to 1 (matches jax.lax.top_k
// tie-breaking: lower flat index wins).
// ---------------------------------------------------------------------------
__global__ __launch_bounds__(256)
void scatter_kernel(const uint32_t* __restrict__ eqCnt, const uint32_t* __restrict__ eqIdx,
                    const uint32_t* __restrict__ Rin, float* __restrict__ out) {
    const int g = blockIdx.x;
    uint32_t E = eqCnt[g];
    const uint32_t R = Rin[g];
    __shared__ uint32_t se[EQCAP];
    for (uint32_t p = threadIdx.x; p < E; p += blockDim.x) se[p] = eqIdx[g * EQCAP + p];
    __syncthreads();
    for (uint32_t p = threadIdx.x; p < E; p += blockDim.x) {
        uint32_t v = se[p], rank = 0;
        for (uint32_t q = 0; q < E; ++q) rank += (se[q] < v) ? 1u : 0u;
        if (rank < R) out[(size_t)g * NNODES * NNODES + v] = 1.0f;
    }
}

extern "C" void kernel_launch(void* const* d_in, const int* in_sizes, int n_in,
                              void* d_out, int out_size, void* d_ws, size_t ws_size,
                              hipStream_t stream) {
    // inputs: x (unused), emb_s [G,N,1], emb_t [G,1,N] -- all float32
    const float* s = (const float*)d_in[1];
    const float* t = (const float*)d_in[2];
    float* out = (float*)d_out;

    char* ws = (char*)d_ws;
    uint32_t* Tbuf  = (uint32_t*)ws; ws += (size_t)NGRAPH * 4;
    uint32_t* Rbuf  = (uint32_t*)ws; ws += (size_t)NGRAPH * 4;
    uint32_t* eqCnt = (uint32_t*)ws; ws += (size_t)NGRAPH * 4;
    uint32_t* eqIdx = (uint32_t*)ws; ws += (size_t)NGRAPH * EQCAP * 4;

    select_kernel<<<NGRAPH, NNODES, 0, stream>>>(s, t, Tbuf, Rbuf, eqCnt, eqIdx);
    write_kernel<<<NGRAPH * NNODES, 256, 0, stream>>>(s, t, Tbuf, out);
    scatter_kernel<<<NGRAPH, 256, 0, stream>>>(eqCnt, eqIdx, Rbuf, out);
}